// Round 21
// baseline (174.165 us; speedup 1.0000x reference)
//
#include <hip/hip_runtime.h>
#include <hip/hip_bf16.h>

typedef __attribute__((ext_vector_type(8))) short bf16x8;
typedef __attribute__((ext_vector_type(4))) float f32x4;
typedef __attribute__((ext_vector_type(16))) float f32x16;

#define S_LEN 2048
#define DMODEL 2048
#define NH 32
#define NKV 8
#define HDIM 64
#define NQKV 3072   // 2048 q + 512 k + 512 v
#define BROWS 4096  // B*S
#define LOG2E 1.4426950408889634f

__device__ __forceinline__ float bf2f(unsigned short u) {
    union { unsigned int i; float f; } v; v.i = ((unsigned int)u) << 16; return v.f;
}
__device__ __forceinline__ unsigned short f2bf(float f) {
    union { float f; unsigned int i; } v; v.f = f;
    unsigned int r = v.i + 0x7fffu + ((v.i >> 16) & 1u);
    return (unsigned short)(r >> 16);
}

__device__ __forceinline__ unsigned cvtpk_bf16(float lo, float hi) {
    unsigned r;
    asm("v_cvt_pk_bf16_f32 %0, %1, %2" : "=v"(r) : "v"(lo), "v"(hi));
    return r;
}
__device__ __forceinline__ void pl32swap(unsigned &a, unsigned &b) {
    asm("v_permlane32_swap_b32 %0, %1" : "+v"(a), "+v"(b));
}
__device__ __forceinline__ float exp2_fast(float x) {
    float r;
    asm("v_exp_f32 %0, %1" : "=v"(r) : "v"(x));
    return r;
}

__device__ __forceinline__ void gload_lds16(const void* g, void* l) {
    __builtin_amdgcn_global_load_lds(
        (const __attribute__((address_space(1))) unsigned int*)(unsigned long long)g,
        (__attribute__((address_space(3))) unsigned int*)(unsigned int)(unsigned long long)l,
        16, 0, 0);
}

#define VMW(n) asm volatile("s_waitcnt vmcnt(" #n ")" ::: "memory")
#define LGW()  asm volatile("s_waitcnt lgkmcnt(0)" ::: "memory")
#define CFENCE() asm volatile("" ::: "memory")
// Buffer-overwrite ordering (neutral-cost, r20-verified): pin MFMAs before
// the pipeline barrier; their compiler-attached lgkm waits then execute
// pre-barrier, so all ds_reads of the reusable buffer complete first.
#define MFMA_PIN() __builtin_amdgcn_sched_barrier(0x3F7)

// ================= fused prep: cast x + transpose-cast all weights =================
__global__ __launch_bounds__(256) void prep_kernel(
    const float* __restrict__ x,
    const float* __restrict__ wq, const float* __restrict__ wk,
    const float* __restrict__ wv, const float* __restrict__ wo,
    unsigned short* __restrict__ xb,
    unsigned short* __restrict__ wqkvT,
    unsigned short* __restrict__ woT) {
    int bid = blockIdx.x;
    if (bid < 8192) {
        int idx = bid * 256 + threadIdx.x;
        float4 v = ((const float4*)x)[idx];
        ushort4 o;
        o.x = f2bf(v.x); o.y = f2bf(v.y); o.z = f2bf(v.z); o.w = f2bf(v.w);
        ((ushort4*)xb)[idx] = o;
        return;
    }
    bid -= 8192;
    const float* src;
    unsigned short* dst;
    int N, nx;
    if (bid < 4096)      { src = wq; dst = wqkvT;                                N = 2048; nx = 64; }
    else if (bid < 5120) { bid -= 4096; src = wk; dst = wqkvT + (size_t)2048 * DMODEL; N = 512; nx = 16; }
    else if (bid < 6144) { bid -= 5120; src = wv; dst = wqkvT + (size_t)2560 * DMODEL; N = 512; nx = 16; }
    else                 { bid -= 6144; src = wo; dst = woT;                     N = 2048; nx = 64; }
    const int K = DMODEL;
    const int n0 = (bid % nx) * 32, k0 = (bid / nx) * 32;
    __shared__ float t[32][33];
    const int tx = threadIdx.x & 31, ty = threadIdx.x >> 5;  // 32 x 8
#pragma unroll
    for (int i = 0; i < 32; i += 8)
        t[ty + i][tx] = src[(size_t)(k0 + ty + i) * N + n0 + tx];
    __syncthreads();
#pragma unroll
    for (int i = 0; i < 32; i += 8)
        dst[(size_t)(n0 + ty + i) * K + k0 + tx] = f2bf(t[tx][ty + i]);
}

// ---------------- transpose V ----------------
__global__ void vtrans_kernel(const unsigned short* __restrict__ qkv,
                              unsigned short* __restrict__ vt) {
    __shared__ unsigned short t[32][33];
    int s0 = blockIdx.x * 32;
    int hd0 = (blockIdx.y & 1) * 32;
    int bg = blockIdx.y >> 1;  // b*8+g
    int b = bg >> 3, g = bg & 7;
    int tx = threadIdx.x & 31, ty = threadIdx.x >> 5;
#pragma unroll
    for (int i = 0; i < 32; i += 8)
        t[ty + i][tx] = qkv[(size_t)(b * S_LEN + s0 + ty + i) * NQKV + 2560 + g * 64 + hd0 + tx];
    __syncthreads();
#pragma unroll
    for (int i = 0; i < 32; i += 8)
        vt[(size_t)(bg * 64 + hd0 + ty + i) * S_LEN + s0 + tx] = t[tx][ty + i];
}

// ================= Wide GEMM: 128 x (NJF*64) tile, BK=64, 32x32x16 MFMA =================
// round-17/20 pipeline structure; inner tile switched 16x16x32 -> 32x32x16
// (attn-verified fragment layout: operand lane=row l31, k-chunk = ks*2+hi;
// C/D row=(reg&3)+8*(reg>>2)+4*hi, col=l31). Per wave: 64x(NCT*32) output,
// NCT=NJF/2 contiguous 32-col tiles. Same LDS layout/swizzle (row offsets
// multiples of 32 -> rA&7 == l31&7), same staging/waits/barriers/MFMA_PIN.
template <int NJF, int OUTF32, int ROPE>
__global__ __launch_bounds__(512, 2) void gemm_wide_kernel(
    const unsigned short* __restrict__ A,
    const unsigned short* __restrict__ BT,
    void* __restrict__ Cv,
    const float* __restrict__ fc, const float* __restrict__ fs,
    int M, int N, int K, int nbx) {
    extern __shared__ __align__(16) unsigned short lds[];
    const int ABUF = 8192;            // u16 per A buffer (128x64)
    const int BSTRIDE = NJF * 4096;   // u16 per B buffer (NJF*64 x 64)
    const int BBASE = 2 * ABUF;
    constexpr int NCT = NJF / 2;      // 32-col tiles per wave

    const int nwg = gridDim.x;
    const int cpx = nwg >> 3;
    const int swz = ((int)blockIdx.x & 7) * cpx + ((int)blockIdx.x >> 3);
    const int m0 = (swz / nbx) * 128, n0 = (swz % nbx) * (NJF * 64);

    const int tid = threadIdx.x;
    const int lane = tid & 63, wid = tid >> 6;
    const int wr = wid >> 2, wc = wid & 3;          // 2 x 4 waves
    const int l31 = lane & 31, hi = lane >> 5;

    const int sr0 = tid >> 3, sk0 = tid & 7;
    const int kc = (sk0 ^ (sr0 & 7)) * 8;           // pre-swizzled global col (u16)
    const size_t K64 = (size_t)64 * K;
    const unsigned short* gA = A + (size_t)(m0 + sr0) * K + kc;
    const unsigned short* gB = BT + (size_t)(n0 + sr0) * K + kc;
    unsigned short* ldsA = lds + tid * 8;
    unsigned short* ldsB = lds + BBASE + tid * 8;

    f32x16 acc[2][NCT];
#pragma unroll
    for (int i = 0; i < 2; ++i)
#pragma unroll
        for (int j = 0; j < NCT; ++j)
#pragma unroll
            for (int e = 0; e < 16; ++e) acc[i][j][e] = 0.f;

    const int NT = K >> 6;
    {
        gload_lds16(gA, ldsA);
        gload_lds16(gA + K64, ldsA + 4096);
#pragma unroll
        for (int j = 0; j < NJF; ++j)
            gload_lds16(gB + (size_t)j * K64, ldsB + j * 4096);
    }

    for (int t = 0; t < NT; ++t) {
        const int cur = t & 1, nxt = cur ^ 1;
        if (t + 1 < NT) {
            gload_lds16(gA + 64, ldsA + nxt * ABUF);
            gload_lds16(gA + 64 + K64, ldsA + nxt * ABUF + 4096);
#pragma unroll
            for (int j = 0; j < NJF; ++j)
                gload_lds16(gB + 64 + (size_t)j * K64, ldsB + nxt * BSTRIDE + j * 4096);
            if constexpr (NJF == 6) { VMW(8); } else { VMW(6); }
        } else {
            VMW(0);
        }
        __builtin_amdgcn_s_barrier();
        CFENCE();

        // compute on cur: 32x32x16 MFMA, K-tile=64 in 4 K-steps of 16
#pragma unroll
        for (int ks = 0; ks < 4; ++ks) {
            bf16x8 af[2], bfv[NCT];
#pragma unroll
            for (int mi = 0; mi < 2; ++mi) {
                const int rA = wr * 64 + mi * 32 + l31;
                af[mi] = *(const bf16x8*)(lds + cur * ABUF + rA * 64 + (((ks * 2 + hi) ^ (rA & 7)) * 8));
            }
#pragma unroll
            for (int nj = 0; nj < NCT; ++nj) {
                const int rB = wc * (NCT * 32) + nj * 32 + l31;
                bfv[nj] = *(const bf16x8*)(lds + BBASE + cur * BSTRIDE + rB * 64 + (((ks * 2 + hi) ^ (rB & 7)) * 8));
            }
#pragma unroll
            for (int mi = 0; mi < 2; ++mi)
#pragma unroll
                for (int nj = 0; nj < NCT; ++nj)
                    acc[mi][nj] = __builtin_amdgcn_mfma_f32_32x32x16_bf16(
                        af[mi], bfv[nj], acc[mi][nj], 0, 0, 0);
        }
        MFMA_PIN();                     // MFMAs (+ their lgkm waits) stay pre-barrier
        __builtin_amdgcn_s_barrier();   // -> next iter may overwrite cur
        CFENCE();
        gA += 64;
        gB += 64;
    }

    // epilogue: C row = m0+wr*64+mi*32+(reg&3)+8*(reg>>2)+4*hi, col = cbase+l31
    const float QS = 0.125f * LOG2E;
    const int fe = l31 >> 1;
    const bool evenl = !(l31 & 1);
#pragma unroll
    for (int mi = 0; mi < 2; ++mi) {
#pragma unroll
        for (int reg = 0; reg < 16; ++reg) {
            const int row = m0 + wr * 64 + mi * 32 + (reg & 3) + 8 * (reg >> 2) + 4 * hi;
            if (OUTF32) {
                float* Cf = (float*)Cv;
#pragma unroll
                for (int nj = 0; nj < NCT; ++nj)
                    Cf[(size_t)row * N + n0 + wc * (NCT * 32) + nj * 32 + l31] = acc[mi][nj][reg];
            } else if (!ROPE) {
                unsigned short* Cb = (unsigned short*)Cv;
#pragma unroll
                for (int nj = 0; nj < NCT; ++nj)
                    Cb[(size_t)row * N + n0 + wc * (NCT * 32) + nj * 32 + l31] = f2bf(acc[mi][nj][reg]);
            } else {
                unsigned short* Cb = (unsigned short*)Cv;
                const int seq = row & (S_LEN - 1);
                const float cA = fc[seq * 32 + fe],      sA = fs[seq * 32 + fe];
                const float cB = fc[seq * 32 + 16 + fe], sB = fs[seq * 32 + 16 + fe];
#pragma unroll
                for (int nj = 0; nj < NCT; ++nj) {
                    const int cbase = n0 + wc * (NCT * 32) + nj * 32;  // wave-uniform, 32-aligned
                    float v = acc[mi][nj][reg];
                    float o;
                    if (cbase >= 2560) {
                        o = v;                         // V: no rope
                    } else {
                        const int p = (wc * NCT + nj) & 1;   // (col&63)>=32 ?
                        float pr = __shfl_xor(v, 1);         // pair partner (col^1 == lane^1)
                        float c = p ? cB : cA, s = p ? sB : sA;
                        o = fmaf(v, c, evenl ? -(pr * s) : (pr * s));
                        if (cbase < 2048) o *= QS;     // Q: fold log2e/sqrt(hd)
                    }
                    Cb[(size_t)row * N + cbase + l31] = f2bf(o);
                }
            }
        }
    }
}

// ---------------- fallback 128x128 GEMM ----------------
template <int OUTF32>
__global__ __launch_bounds__(256) void gemm_bt_kernel(
    const unsigned short* __restrict__ A,
    const unsigned short* __restrict__ BT,
    void* __restrict__ Cv,
    int M, int N, int K) {
    __shared__ __align__(16) unsigned short Als[128 * 32];
    __shared__ __align__(16) unsigned short Bls[128 * 32];

    const int tid = threadIdx.x;
    const int lane = tid & 63;
    const int wid = tid >> 6;
    const int wr = wid >> 1, wc = wid & 1;
    const int l16 = lane & 15, lg = lane >> 4;
    const int m0 = blockIdx.y * 128, n0 = blockIdx.x * 128;

    f32x4 acc[4][4];
#pragma unroll
    for (int i = 0; i < 4; ++i)
#pragma unroll
        for (int j = 0; j < 4; ++j)
#pragma unroll
            for (int e = 0; e < 4; ++e) acc[i][j][e] = 0.f;

    const int f0 = tid, f1 = 256 + tid;
    const int ar0 = f0 >> 2, ac0 = (f0 & 3) * 8;
    const int ar1 = f1 >> 2, ac1 = (f1 & 3) * 8;
    const size_t Abase = (size_t)m0 * K;
    const size_t Bbase = (size_t)n0 * K;

    for (int k0 = 0; k0 < K; k0 += 32) {
        __syncthreads();
        gload_lds16(A + Abase + (size_t)ar0 * K + k0 + ac0, Als + f0 * 8);
        gload_lds16(A + Abase + (size_t)ar1 * K + k0 + ac1, Als + f1 * 8);
        gload_lds16(BT + Bbase + (size_t)ar0 * K + k0 + ac0, Bls + f0 * 8);
        gload_lds16(BT + Bbase + (size_t)ar1 * K + k0 + ac1, Bls + f1 * 8);
        __syncthreads();
        bf16x8 af[4], bfv[4];
#pragma unroll
        for (int i = 0; i < 4; ++i)
            af[i] = *(const bf16x8*)(Als + (wr * 64 + i * 16 + l16) * 32 + lg * 8);
#pragma unroll
        for (int j = 0; j < 4; ++j)
            bfv[j] = *(const bf16x8*)(Bls + (wc * 64 + j * 16 + l16) * 32 + lg * 8);
#pragma unroll
        for (int i = 0; i < 4; ++i)
#pragma unroll
            for (int j = 0; j < 4; ++j)
                acc[i][j] = __builtin_amdgcn_mfma_f32_16x16x32_bf16(af[i], bfv[j], acc[i][j], 0, 0, 0);
    }

    const int row_base = m0 + wr * 64 + lg * 4;
    const int col_base = n0 + wc * 64 + l16;
    if (OUTF32) {
        float* Cf = (float*)Cv;
#pragma unroll
        for (int i = 0; i < 4; ++i)
#pragma unroll
            for (int r = 0; r < 4; ++r)
#pragma unroll
                for (int j = 0; j < 4; ++j)
                    Cf[(size_t)(row_base + i * 16 + r) * N + col_base + j * 16] = acc[i][j][r];
    } else {
        unsigned short* Cb = (unsigned short*)Cv;
#pragma unroll
        for (int i = 0; i < 4; ++i)
#pragma unroll
            for (int r = 0; r < 4; ++r)
#pragma unroll
                for (int j = 0; j < 4; ++j)
                    Cb[(size_t)(row_base + i * 16 + r) * N + col_base + j * 16] = f2bf(acc[i][j][r]);
    }
}

// ---------------- standalone RoPE (fallback path only) ----------------
__global__ void rope_kernel(unsigned short* __restrict__ qkv,
                            const float* __restrict__ fc, const float* __restrict__ fs) {
    const int PAIRS = 1280;
    int idx = blockIdx.x * blockDim.x + threadIdx.x;
    int row = idx / PAIRS;
    int w = idx - row * PAIRS;
    int s = row & (S_LEN - 1);
    int col = (w < 1024) ? (w * 2) : (2048 + (w - 1024) * 2);
    int f = (col & 63) >> 1;
    float c = fc[s * 32 + f], sn = fs[s * 32 + f];
    unsigned int* p = (unsigned int*)(qkv + (size_t)row * NQKV + col);
    unsigned int v = *p;
    float re = bf2f((unsigned short)(v & 0xffffu));
    float im = bf2f((unsigned short)(v >> 16));
    float oro = re * c - im * sn;
    float oim = re * sn + im * c;
    if (w < 1024) { oro *= 0.125f * LOG2E; oim *= 0.125f * LOG2E; }
    *p = (unsigned int)f2bf(oro) | ((unsigned int)f2bf(oim) << 16);
}

// ---------------- flash attention: PAIRED q-chunks, shared K/V staging ----------------
// (round-16/17/19/20 proven version, unchanged)
__global__ __launch_bounds__(512) void attn_kernel(
    const unsigned short* __restrict__ qkv,
    const unsigned short* __restrict__ vt,
    unsigned short* __restrict__ aout) {
    __shared__ __align__(16) unsigned short Kls[2][64 * 64];
    __shared__ __align__(16) unsigned short Vls[2][64 * 64];
    __shared__ float Fbuf[8][32];

    const int tid = threadIdx.x, lane = tid & 63, wid = tid >> 6;
    const int l31 = lane & 31, hi = lane >> 5;
    const int g = blockIdx.x, b = blockIdx.y;
    const int h = g * 4 + (wid & 3);
    const int cw = wid >> 2;                      // 0: chunk 2z, 1: chunk 2z+1

    const int srow = tid >> 3, schk = tid & 7;
    const int sc = schk ^ (srow & 7);             // pre-swizzled source chunk
    const unsigned short* kgs = qkv + (size_t)(b * S_LEN + srow) * NQKV + 2048 + g * 64 + sc * 8;
    const unsigned short* vgs = vt + (size_t)((b * 8 + g) * 64 + srow) * S_LEN + sc * 8;
    const int dd = tid * 8;

    const int xr = l31 & 7;

    const int z = 31 - (int)blockIdx.z;
    const int chunk = 2 * z + cw;
    const int q0 = chunk * 32;
    const int ntiles = z + 1;
    const int qg_row = q0 + l31;

    bf16x8 qf[4];
    {
        const unsigned short* qp =
            qkv + (size_t)(b * S_LEN + q0 + l31) * NQKV + h * HDIM + hi * 8;
#pragma unroll
        for (int s = 0; s < 4; ++s) qf[s] = *(const bf16x8*)(qp + s * 16);
    }

    float l_r = 0.f;
    f32x16 oacc0, oacc1;
#pragma unroll
    for (int r = 0; r < 16; ++r) { oacc0[r] = 0.f; oacc1[r] = 0.f; }

    gload_lds16(kgs, Kls[0] + dd);
    gload_lds16(vgs, Vls[0] + dd);
    __syncthreads();

    for (int t = 0; t < ntiles; ++t) {
        const int kv0 = t * 64;
        if (t + 1 < ntiles) {
            const int nkv = kv0 + 64;
            gload_lds16(kgs + (size_t)nkv * NQKV, Kls[(t + 1) & 1] + dd);
            gload_lds16(vgs + nkv, Vls[(t + 1) & 1] + dd);
        }
        const unsigned short* Kb = Kls[t & 1];
        const unsigned short* Vb = Vls[t & 1];

        // QK^T (swapped)
        f32x16 s0, s1;
#pragma unroll
        for (int r = 0; r < 16; ++r) { s0[r] = 0.f; s1[r] = 0.f; }
        __builtin_amdgcn_s_setprio(1);
#pragma unroll
        for (int s = 0; s < 4; ++s) {
            const int coff = ((s * 2 + hi) ^ xr) * 8;
            bf16x8 kf0 = *(const bf16x8*)(Kb + l31 * 64 + coff);
            bf16x8 kf1 = *(const bf16x8*)(Kb + (32 + l31) * 64 + coff);
            s0 = __builtin_amdgcn_mfma_f32_32x32x16_bf16(kf0, qf[s], s0, 0, 0, 0);
            s1 = __builtin_amdgcn_mfma_f32_32x32x16_bf16(kf1, qf[s], s1, 0, 0, 0);
        }
        __builtin_amdgcn_s_setprio(0);
        if (t == ntiles - 1) {
#pragma unroll
            for (int r = 0; r < 16; ++r) {
                int kvr = kv0 + (r & 3) + 8 * (r >> 2) + 4 * hi;
                if (kvr > qg_row) s0[r] = -3.0e38f;
                if (kvr + 32 > qg_row) s1[r] = -3.0e38f;
            }
        }
        // streaming softmax, no max: p = exp2(s), local sum only
        float r0 = 0.f, r1 = 0.f, r2 = 0.f, r3 = 0.f;
#pragma unroll
        for (int r = 0; r < 16; r += 4) {
            s0[r + 0] = exp2_fast(s0[r + 0]); r0 += s0[r + 0];
            s0[r + 1] = exp2_fast(s0[r + 1]); r1 += s0[r + 1];
            s0[r + 2] = exp2_fast(s0[r + 2]); r2 += s0[r + 2];
            s0[r + 3] = exp2_fast(s0[r + 3]); r3 += s0[r + 3];
        }
#pragma unroll
        for (int r = 0; r < 16; r += 4) {
            s1[r + 0] = exp2_fast(s1[r + 0]); r0 += s1[r + 0];
            s1[r + 1] = exp2_fast(s1[r + 1]); r1 += s1[r + 1];
            s1[r + 2] = exp2_fast(s1[r + 2]); r2 += s1[r + 2];
            s1[r + 3] = exp2_fast(s1[r + 3]); r3 += s1[r + 3];
        }
        l_r += (r0 + r1) + (r2 + r3);

        unsigned pw[4][4];
#define BUILD_PA(c, S, base)                                    \
        {                                                       \
            unsigned x0 = cvtpk_bf16(S[base + 0], S[base + 1]); \
            unsigned y0 = cvtpk_bf16(S[base + 4], S[base + 5]); \
            pl32swap(x0, y0);                                   \
            unsigned x1 = cvtpk_bf16(S[base + 2], S[base + 3]); \
            unsigned y1 = cvtpk_bf16(S[base + 6], S[base + 7]); \
            pl32swap(x1, y1);                                   \
            pw[c][0] = x0; pw[c][1] = x1; pw[c][2] = y0; pw[c][3] = y1; \
        }
        BUILD_PA(0, s0, 0)
        BUILD_PA(1, s0, 8)
        BUILD_PA(2, s1, 0)
        BUILD_PA(3, s1, 8)
#undef BUILD_PA

        __builtin_amdgcn_s_setprio(1);
#pragma unroll
        for (int c = 0; c < 4; ++c) {
            union { unsigned u[4]; bf16x8 v; } pa;
            pa.u[0] = pw[c][0]; pa.u[1] = pw[c][1]; pa.u[2] = pw[c][2]; pa.u[3] = pw[c][3];
            const int coff = ((c * 2 + hi) ^ xr) * 8;
            bf16x8 vf0 = *(const bf16x8*)(Vb + l31 * 64 + coff);
            bf16x8 vf1 = *(const bf16x8*)(Vb + (32 + l31) * 64 + coff);
            oacc0 = __builtin_amdgcn_mfma_f32_32x32x16_bf16(pa.v, vf0, oacc0, 0, 0, 0);
            oacc1 = __builtin_amdgcn_mfma_f32_32x32x16_bf16(pa.v, vf1, oacc1, 0, 0, 0);
        }
        __builtin_amdgcn_s_setprio(0);
        __syncthreads();
    }

    // epilogue: combine half-row partials, broadcast 1/l, write O
    l_r += __shfl_xor(l_r, 32);
    if (lane < 32) Fbuf[wid][l31] = 1.0f / l_r;
    asm volatile("s_waitcnt lgkmcnt(0)" ::: "memory");
#pragma unroll
    for (int rg = 0; rg < 4; ++rg) {
#pragma unroll
        for (int rr = 0; rr < 4; ++rr) {
            int row = 8 * rg + 4 * hi + rr;
            float inv = Fbuf[wid][row];
            int r = rg * 4 + rr;
            size_t orow = (size_t)(b * S_LEN + q0 + row) * DMODEL + h * HDIM;
            aout[orow + l31] = f2bf(oacc0[r] * inv);
            aout[orow + 32 + l31] = f2bf(oacc1[r] * inv);
        }
    }
}

extern "C" void kernel_launch(void* const* d_in, const int* in_sizes, int n_in,
                              void* d_out, int out_size, void* d_ws, size_t ws_size,
                              hipStream_t stream) {
    const float* x = (const float*)d_in[0];
    const float* wq = (const float*)d_in[1];
    const float* wk = (const float*)d_in[2];
    const float* wv = (const float*)d_in[3];
    const float* wo = (const float*)d_in[4];
    const float* fc = (const float*)d_in[5];
    const float* fs = (const float*)d_in[6];
    float* out = (float*)d_out;

    unsigned short* xb = (unsigned short*)d_ws;                 // 4096x2048
    unsigned short* wqkvT = xb + (size_t)BROWS * DMODEL;        // 3072x2048
    unsigned short* woT = wqkvT + (size_t)NQKV * DMODEL;        // 2048x2048
    unsigned short* qkvb = woT + (size_t)DMODEL * DMODEL;       // 4096x3072
    unsigned short* aoutb = xb;                                 // reuse xb after GEMM1
    unsigned short* vtb = wqkvT;                                // reuse wqkvT after GEMM1

    hipError_t e1 = hipFuncSetAttribute(
        reinterpret_cast<const void*>(&gemm_wide_kernel<6, 0, 1>),
        hipFuncAttributeMaxDynamicSharedMemorySize, 131072);
    hipError_t e2 = hipFuncSetAttribute(
        reinterpret_cast<const void*>(&gemm_wide_kernel<4, 1, 0>),
        hipFuncAttributeMaxDynamicSharedMemorySize, 98304);
    const bool big = (e1 == hipSuccess && e2 == hipSuccess);

    // 1. fused prep: cast x + transpose-cast all weights (one launch)
    prep_kernel<<<18432, 256, 0, stream>>>(x, wq, wk, wv, wo, xb, wqkvT, woT);
    // 2. QKV GEMM + fused RoPE: 256 blocks, 128x384 tile
    if (big) {
        gemm_wide_kernel<6, 0, 1><<<(BROWS / 128) * (NQKV / 384), 512, 131072, stream>>>(
            xb, wqkvT, qkvb, fc, fs, BROWS, NQKV, DMODEL, NQKV / 384);
    } else {
        gemm_bt_kernel<0><<<dim3(NQKV / 128, BROWS / 128), 256, 0, stream>>>(
            xb, wqkvT, qkvb, BROWS, NQKV, DMODEL);
        rope_kernel<<<(BROWS * 1280) / 256, 256, 0, stream>>>(qkvb, fc, fs);
    }
    // 3. V transpose
    vtrans_kernel<<<dim3(S_LEN / 32, 32), 256, 0, stream>>>(qkvb, vtb);
    // 4. attention: 512 paired blocks (chunks {2z,2z+1} share K/V staging)
    attn_kernel<<<dim3(NKV, 2, 32), 512, 0, stream>>>(qkvb, vtb, aoutb);
    // 5. output GEMM: out = aoutb @ woT^T (4096x2048 f32), 128x256 tile
    if (big)
        gemm_wide_kernel<4, 1, 0><<<(BROWS / 128) * (DMODEL / 256), 512, 98304, stream>>>(
            aoutb, woT, out, nullptr, nullptr, BROWS, DMODEL, DMODEL, DMODEL / 256);
    else
        gemm_bt_kernel<1><<<dim3(DMODEL / 128, BROWS / 128), 256, 0, stream>>>(
            aoutb, woT, out, BROWS, DMODEL, DMODEL);
}

// Round 22
// 166.748 us; speedup vs baseline: 1.0445x; 1.0445x over previous
//
#include <hip/hip_runtime.h>
#include <hip/hip_bf16.h>

typedef __attribute__((ext_vector_type(8))) short bf16x8;
typedef __attribute__((ext_vector_type(4))) float f32x4;
typedef __attribute__((ext_vector_type(16))) float f32x16;

#define S_LEN 2048
#define DMODEL 2048
#define NH 32
#define NKV 8
#define HDIM 64
#define NQKV 3072   // 2048 q + 512 k + 512 v
#define BROWS 4096  // B*S
#define LOG2E 1.4426950408889634f

__device__ __forceinline__ float bf2f(unsigned short u) {
    union { unsigned int i; float f; } v; v.i = ((unsigned int)u) << 16; return v.f;
}
__device__ __forceinline__ unsigned short f2bf(float f) {
    union { float f; unsigned int i; } v; v.f = f;
    unsigned int r = v.i + 0x7fffu + ((v.i >> 16) & 1u);
    return (unsigned short)(r >> 16);
}

__device__ __forceinline__ unsigned cvtpk_bf16(float lo, float hi) {
    unsigned r;
    asm("v_cvt_pk_bf16_f32 %0, %1, %2" : "=v"(r) : "v"(lo), "v"(hi));
    return r;
}
__device__ __forceinline__ void pl32swap(unsigned &a, unsigned &b) {
    asm("v_permlane32_swap_b32 %0, %1" : "+v"(a), "+v"(b));
}
__device__ __forceinline__ float exp2_fast(float x) {
    float r;
    asm("v_exp_f32 %0, %1" : "=v"(r) : "v"(x));
    return r;
}

__device__ __forceinline__ void gload_lds16(const void* g, void* l) {
    __builtin_amdgcn_global_load_lds(
        (const __attribute__((address_space(1))) unsigned int*)(unsigned long long)g,
        (__attribute__((address_space(3))) unsigned int*)(unsigned int)(unsigned long long)l,
        16, 0, 0);
}

#define VMW(n) asm volatile("s_waitcnt vmcnt(" #n ")" ::: "memory")
#define LGW()  asm volatile("s_waitcnt lgkmcnt(0)" ::: "memory")
#define CFENCE() asm volatile("" ::: "memory")
// Buffer-overwrite ordering (neutral-cost, r20-verified): pin MFMAs before
// the pipeline barrier; their compiler-attached lgkm waits then execute
// pre-barrier, so all ds_reads of the reusable buffer complete first.
// NOTE (r21): 16x16x32 fragments are the right shape for the [row][64]
// LDS layout — 16 distinct rows/wave -> 2-way bank aliasing (free, m136);
// 32x32x16 spans 32 rows -> unavoidable 4-way conflict (bank = chunk*4%32).
#define MFMA_PIN() __builtin_amdgcn_sched_barrier(0x3F7)

// ================= fused prep: cast x + transpose-cast all weights =================
__global__ __launch_bounds__(256) void prep_kernel(
    const float* __restrict__ x,
    const float* __restrict__ wq, const float* __restrict__ wk,
    const float* __restrict__ wv, const float* __restrict__ wo,
    unsigned short* __restrict__ xb,
    unsigned short* __restrict__ wqkvT,
    unsigned short* __restrict__ woT) {
    int bid = blockIdx.x;
    if (bid < 8192) {
        int idx = bid * 256 + threadIdx.x;
        float4 v = ((const float4*)x)[idx];
        ushort4 o;
        o.x = f2bf(v.x); o.y = f2bf(v.y); o.z = f2bf(v.z); o.w = f2bf(v.w);
        ((ushort4*)xb)[idx] = o;
        return;
    }
    bid -= 8192;
    const float* src;
    unsigned short* dst;
    int N, nx;
    if (bid < 4096)      { src = wq; dst = wqkvT;                                N = 2048; nx = 64; }
    else if (bid < 5120) { bid -= 4096; src = wk; dst = wqkvT + (size_t)2048 * DMODEL; N = 512; nx = 16; }
    else if (bid < 6144) { bid -= 5120; src = wv; dst = wqkvT + (size_t)2560 * DMODEL; N = 512; nx = 16; }
    else                 { bid -= 6144; src = wo; dst = woT;                     N = 2048; nx = 64; }
    const int K = DMODEL;
    const int n0 = (bid % nx) * 32, k0 = (bid / nx) * 32;
    __shared__ float t[32][33];
    const int tx = threadIdx.x & 31, ty = threadIdx.x >> 5;  // 32 x 8
#pragma unroll
    for (int i = 0; i < 32; i += 8)
        t[ty + i][tx] = src[(size_t)(k0 + ty + i) * N + n0 + tx];
    __syncthreads();
#pragma unroll
    for (int i = 0; i < 32; i += 8)
        dst[(size_t)(n0 + ty + i) * K + k0 + tx] = f2bf(t[tx][ty + i]);
}

// ---------------- transpose V ----------------
__global__ void vtrans_kernel(const unsigned short* __restrict__ qkv,
                              unsigned short* __restrict__ vt) {
    __shared__ unsigned short t[32][33];
    int s0 = blockIdx.x * 32;
    int hd0 = (blockIdx.y & 1) * 32;
    int bg = blockIdx.y >> 1;  // b*8+g
    int b = bg >> 3, g = bg & 7;
    int tx = threadIdx.x & 31, ty = threadIdx.x >> 5;
#pragma unroll
    for (int i = 0; i < 32; i += 8)
        t[ty + i][tx] = qkv[(size_t)(b * S_LEN + s0 + ty + i) * NQKV + 2560 + g * 64 + hd0 + tx];
    __syncthreads();
#pragma unroll
    for (int i = 0; i < 32; i += 8)
        vt[(size_t)(bg * 64 + hd0 + ty + i) * S_LEN + s0 + tx] = t[tx][ty + i];
}

// ================= Wide GEMM: 128 x (NJF*64) tile, BK=64, 2-barrier/K-tile =================
// (round-20 best-verified version, unchanged)
template <int NJF, int OUTF32, int ROPE>
__global__ __launch_bounds__(512, 2) void gemm_wide_kernel(
    const unsigned short* __restrict__ A,
    const unsigned short* __restrict__ BT,
    void* __restrict__ Cv,
    const float* __restrict__ fc, const float* __restrict__ fs,
    int M, int N, int K, int nbx) {
    extern __shared__ __align__(16) unsigned short lds[];
    const int ABUF = 8192;            // u16 per A buffer (128x64)
    const int BSTRIDE = NJF * 4096;   // u16 per B buffer (NJF*64 x 64)
    const int BBASE = 2 * ABUF;

    const int nwg = gridDim.x;
    const int cpx = nwg >> 3;
    const int swz = ((int)blockIdx.x & 7) * cpx + ((int)blockIdx.x >> 3);
    const int m0 = (swz / nbx) * 128, n0 = (swz % nbx) * (NJF * 64);

    const int tid = threadIdx.x;
    const int lane = tid & 63, wid = tid >> 6;
    const int wr = wid >> 2, wc = wid & 3;          // 2 x 4 waves
    const int l16 = lane & 15, lg = lane >> 4;

    const int sr0 = tid >> 3, sk0 = tid & 7;
    const int kc = (sk0 ^ (sr0 & 7)) * 8;           // pre-swizzled global col (u16)
    const size_t K64 = (size_t)64 * K;
    const unsigned short* gA = A + (size_t)(m0 + sr0) * K + kc;
    const unsigned short* gB = BT + (size_t)(n0 + sr0) * K + kc;
    unsigned short* ldsA = lds + tid * 8;
    unsigned short* ldsB = lds + BBASE + tid * 8;

    f32x4 acc[4][NJF];
#pragma unroll
    for (int i = 0; i < 4; ++i)
#pragma unroll
        for (int j = 0; j < NJF; ++j)
#pragma unroll
            for (int e = 0; e < 4; ++e) acc[i][j][e] = 0.f;

    const int NT = K >> 6;
    {
        gload_lds16(gA, ldsA);
        gload_lds16(gA + K64, ldsA + 4096);
#pragma unroll
        for (int j = 0; j < NJF; ++j)
            gload_lds16(gB + (size_t)j * K64, ldsB + j * 4096);
    }

    for (int t = 0; t < NT; ++t) {
        const int cur = t & 1, nxt = cur ^ 1;
        if (t + 1 < NT) {
            gload_lds16(gA + 64, ldsA + nxt * ABUF);
            gload_lds16(gA + 64 + K64, ldsA + nxt * ABUF + 4096);
#pragma unroll
            for (int j = 0; j < NJF; ++j)
                gload_lds16(gB + 64 + (size_t)j * K64, ldsB + nxt * BSTRIDE + j * 4096);
            if constexpr (NJF == 6) { VMW(8); } else { VMW(6); }
        } else {
            VMW(0);
        }
        __builtin_amdgcn_s_barrier();
        CFENCE();

#pragma unroll
        for (int ks = 0; ks < 2; ++ks) {
            bf16x8 af[4], bfv[NJF];
#pragma unroll
            for (int mi = 0; mi < 4; ++mi) {
                const int rA = wr * 64 + mi * 16 + l16;
                af[mi] = *(const bf16x8*)(lds + cur * ABUF + rA * 64 + ((ks * 4 + lg) ^ (rA & 7)) * 8);
            }
#pragma unroll
            for (int nj = 0; nj < NJF; ++nj) {
                const int rB = nj * 64 + wc * 16 + l16;
                bfv[nj] = *(const bf16x8*)(lds + BBASE + cur * BSTRIDE + rB * 64 + ((ks * 4 + lg) ^ (rB & 7)) * 8);
            }
#pragma unroll
            for (int mi = 0; mi < 4; ++mi)
#pragma unroll
                for (int nj = 0; nj < NJF; ++nj)
                    acc[mi][nj] = __builtin_amdgcn_mfma_f32_16x16x32_bf16(
                        af[mi], bfv[nj], acc[mi][nj], 0, 0, 0);
        }
        MFMA_PIN();                     // MFMAs (+ their lgkm waits) stay pre-barrier
        __builtin_amdgcn_s_barrier();   // -> next iter may overwrite cur
        CFENCE();
        gA += 64;
        gB += 64;
    }

    const float QS = 0.125f * LOG2E;
    const int fidx = (wc * 16 + l16) >> 1;
    const bool evenl = !(l16 & 1);
#pragma unroll
    for (int mi = 0; mi < 4; ++mi) {
        const int row = m0 + wr * 64 + mi * 16 + lg * 4;
#pragma unroll
        for (int e = 0; e < 4; ++e) {
            if (OUTF32) {
                float* Cf = (float*)Cv;
#pragma unroll
                for (int nj = 0; nj < NJF; ++nj)
                    Cf[(size_t)(row + e) * N + n0 + nj * 64 + wc * 16 + l16] = acc[mi][nj][e];
            } else if (!ROPE) {
                unsigned short* Cb = (unsigned short*)Cv;
#pragma unroll
                for (int nj = 0; nj < NJF; ++nj)
                    Cb[(size_t)(row + e) * N + n0 + nj * 64 + wc * 16 + l16] = f2bf(acc[mi][nj][e]);
            } else {
                unsigned short* Cb = (unsigned short*)Cv;
                const int seq = (row + e) & (S_LEN - 1);
                const float c = fc[seq * 32 + fidx], s = fs[seq * 32 + fidx];
#pragma unroll
                for (int nj = 0; nj < NJF; ++nj) {
                    const int cbase = n0 + nj * 64 + wc * 16;
                    float v = acc[mi][nj][e];
                    float o;
                    if (cbase >= 2560) {
                        o = v;
                    } else {
                        float p = __shfl_xor(v, 1);
                        o = fmaf(v, c, evenl ? -(p * s) : (p * s));
                        if (cbase < 2048) o *= QS;
                    }
                    Cb[(size_t)(row + e) * N + cbase + l16] = f2bf(o);
                }
            }
        }
    }
}

// ---------------- fallback 128x128 GEMM ----------------
template <int OUTF32>
__global__ __launch_bounds__(256) void gemm_bt_kernel(
    const unsigned short* __restrict__ A,
    const unsigned short* __restrict__ BT,
    void* __restrict__ Cv,
    int M, int N, int K) {
    __shared__ __align__(16) unsigned short Als[128 * 32];
    __shared__ __align__(16) unsigned short Bls[128 * 32];

    const int tid = threadIdx.x;
    const int lane = tid & 63;
    const int wid = tid >> 6;
    const int wr = wid >> 1, wc = wid & 1;
    const int l16 = lane & 15, lg = lane >> 4;
    const int m0 = blockIdx.y * 128, n0 = blockIdx.x * 128;

    f32x4 acc[4][4];
#pragma unroll
    for (int i = 0; i < 4; ++i)
#pragma unroll
        for (int j = 0; j < 4; ++j)
#pragma unroll
            for (int e = 0; e < 4; ++e) acc[i][j][e] = 0.f;

    const int f0 = tid, f1 = 256 + tid;
    const int ar0 = f0 >> 2, ac0 = (f0 & 3) * 8;
    const int ar1 = f1 >> 2, ac1 = (f1 & 3) * 8;
    const size_t Abase = (size_t)m0 * K;
    const size_t Bbase = (size_t)n0 * K;

    for (int k0 = 0; k0 < K; k0 += 32) {
        __syncthreads();
        gload_lds16(A + Abase + (size_t)ar0 * K + k0 + ac0, Als + f0 * 8);
        gload_lds16(A + Abase + (size_t)ar1 * K + k0 + ac1, Als + f1 * 8);
        gload_lds16(BT + Bbase + (size_t)ar0 * K + k0 + ac0, Bls + f0 * 8);
        gload_lds16(BT + Bbase + (size_t)ar1 * K + k0 + ac1, Bls + f1 * 8);
        __syncthreads();
        bf16x8 af[4], bfv[4];
#pragma unroll
        for (int i = 0; i < 4; ++i)
            af[i] = *(const bf16x8*)(Als + (wr * 64 + i * 16 + l16) * 32 + lg * 8);
#pragma unroll
        for (int j = 0; j < 4; ++j)
            bfv[j] = *(const bf16x8*)(Bls + (wc * 64 + j * 16 + l16) * 32 + lg * 8);
#pragma unroll
        for (int i = 0; i < 4; ++i)
#pragma unroll
            for (int j = 0; j < 4; ++j)
                acc[i][j] = __builtin_amdgcn_mfma_f32_16x16x32_bf16(af[i], bfv[j], acc[i][j], 0, 0, 0);
    }

    const int row_base = m0 + wr * 64 + lg * 4;
    const int col_base = n0 + wc * 64 + l16;
    if (OUTF32) {
        float* Cf = (float*)Cv;
#pragma unroll
        for (int i = 0; i < 4; ++i)
#pragma unroll
            for (int r = 0; r < 4; ++r)
#pragma unroll
                for (int j = 0; j < 4; ++j)
                    Cf[(size_t)(row_base + i * 16 + r) * N + col_base + j * 16] = acc[i][j][r];
    } else {
        unsigned short* Cb = (unsigned short*)Cv;
#pragma unroll
        for (int i = 0; i < 4; ++i)
#pragma unroll
            for (int r = 0; r < 4; ++r)
#pragma unroll
                for (int j = 0; j < 4; ++j)
                    Cb[(size_t)(row_base + i * 16 + r) * N + col_base + j * 16] = f2bf(acc[i][j][r]);
    }
}

// ---------------- standalone RoPE (fallback path only) ----------------
__global__ void rope_kernel(unsigned short* __restrict__ qkv,
                            const float* __restrict__ fc, const float* __restrict__ fs) {
    const int PAIRS = 1280;
    int idx = blockIdx.x * blockDim.x + threadIdx.x;
    int row = idx / PAIRS;
    int w = idx - row * PAIRS;
    int s = row & (S_LEN - 1);
    int col = (w < 1024) ? (w * 2) : (2048 + (w - 1024) * 2);
    int f = (col & 63) >> 1;
    float c = fc[s * 32 + f], sn = fs[s * 32 + f];
    unsigned int* p = (unsigned int*)(qkv + (size_t)row * NQKV + col);
    unsigned int v = *p;
    float re = bf2f((unsigned short)(v & 0xffffu));
    float im = bf2f((unsigned short)(v >> 16));
    float oro = re * c - im * sn;
    float oim = re * sn + im * c;
    if (w < 1024) { oro *= 0.125f * LOG2E; oim *= 0.125f * LOG2E; }
    *p = (unsigned int)f2bf(oro) | ((unsigned int)f2bf(oim) << 16);
}

// ---------------- flash attention: PAIRED q-chunks, shared K/V staging ----------------
// (round-16/17/19/20 proven version, unchanged)
__global__ __launch_bounds__(512) void attn_kernel(
    const unsigned short* __restrict__ qkv,
    const unsigned short* __restrict__ vt,
    unsigned short* __restrict__ aout) {
    __shared__ __align__(16) unsigned short Kls[2][64 * 64];
    __shared__ __align__(16) unsigned short Vls[2][64 * 64];
    __shared__ float Fbuf[8][32];

    const int tid = threadIdx.x, lane = tid & 63, wid = tid >> 6;
    const int l31 = lane & 31, hi = lane >> 5;
    const int g = blockIdx.x, b = blockIdx.y;
    const int h = g * 4 + (wid & 3);
    const int cw = wid >> 2;                      // 0: chunk 2z, 1: chunk 2z+1

    const int srow = tid >> 3, schk = tid & 7;
    const int sc = schk ^ (srow & 7);             // pre-swizzled source chunk
    const unsigned short* kgs = qkv + (size_t)(b * S_LEN + srow) * NQKV + 2048 + g * 64 + sc * 8;
    const unsigned short* vgs = vt + (size_t)((b * 8 + g) * 64 + srow) * S_LEN + sc * 8;
    const int dd = tid * 8;

    const int xr = l31 & 7;

    const int z = 31 - (int)blockIdx.z;
    const int chunk = 2 * z + cw;
    const int q0 = chunk * 32;
    const int ntiles = z + 1;
    const int qg_row = q0 + l31;

    bf16x8 qf[4];
    {
        const unsigned short* qp =
            qkv + (size_t)(b * S_LEN + q0 + l31) * NQKV + h * HDIM + hi * 8;
#pragma unroll
        for (int s = 0; s < 4; ++s) qf[s] = *(const bf16x8*)(qp + s * 16);
    }

    float l_r = 0.f;
    f32x16 oacc0, oacc1;
#pragma unroll
    for (int r = 0; r < 16; ++r) { oacc0[r] = 0.f; oacc1[r] = 0.f; }

    gload_lds16(kgs, Kls[0] + dd);
    gload_lds16(vgs, Vls[0] + dd);
    __syncthreads();

    for (int t = 0; t < ntiles; ++t) {
        const int kv0 = t * 64;
        if (t + 1 < ntiles) {
            const int nkv = kv0 + 64;
            gload_lds16(kgs + (size_t)nkv * NQKV, Kls[(t + 1) & 1] + dd);
            gload_lds16(vgs + nkv, Vls[(t + 1) & 1] + dd);
        }
        const unsigned short* Kb = Kls[t & 1];
        const unsigned short* Vb = Vls[t & 1];

        // QK^T (swapped)
        f32x16 s0, s1;
#pragma unroll
        for (int r = 0; r < 16; ++r) { s0[r] = 0.f; s1[r] = 0.f; }
        __builtin_amdgcn_s_setprio(1);
#pragma unroll
        for (int s = 0; s < 4; ++s) {
            const int coff = ((s * 2 + hi) ^ xr) * 8;
            bf16x8 kf0 = *(const bf16x8*)(Kb + l31 * 64 + coff);
            bf16x8 kf1 = *(const bf16x8*)(Kb + (32 + l31) * 64 + coff);
            s0 = __builtin_amdgcn_mfma_f32_32x32x16_bf16(kf0, qf[s], s0, 0, 0, 0);
            s1 = __builtin_amdgcn_mfma_f32_32x32x16_bf16(kf1, qf[s], s1, 0, 0, 0);
        }
        __builtin_amdgcn_s_setprio(0);
        if (t == ntiles - 1) {
#pragma unroll
            for (int r = 0; r < 16; ++r) {
                int kvr = kv0 + (r & 3) + 8 * (r >> 2) + 4 * hi;
                if (kvr > qg_row) s0[r] = -3.0e38f;
                if (kvr + 32 > qg_row) s1[r] = -3.0e38f;
            }
        }
        // streaming softmax, no max: p = exp2(s), local sum only
        float r0 = 0.f, r1 = 0.f, r2 = 0.f, r3 = 0.f;
#pragma unroll
        for (int r = 0; r < 16; r += 4) {
            s0[r + 0] = exp2_fast(s0[r + 0]); r0 += s0[r + 0];
            s0[r + 1] = exp2_fast(s0[r + 1]); r1 += s0[r + 1];
            s0[r + 2] = exp2_fast(s0[r + 2]); r2 += s0[r + 2];
            s0[r + 3] = exp2_fast(s0[r + 3]); r3 += s0[r + 3];
        }
#pragma unroll
        for (int r = 0; r < 16; r += 4) {
            s1[r + 0] = exp2_fast(s1[r + 0]); r0 += s1[r + 0];
            s1[r + 1] = exp2_fast(s1[r + 1]); r1 += s1[r + 1];
            s1[r + 2] = exp2_fast(s1[r + 2]); r2 += s1[r + 2];
            s1[r + 3] = exp2_fast(s1[r + 3]); r3 += s1[r + 3];
        }
        l_r += (r0 + r1) + (r2 + r3);

        unsigned pw[4][4];
#define BUILD_PA(c, S, base)                                    \
        {                                                       \
            unsigned x0 = cvtpk_bf16(S[base + 0], S[base + 1]); \
            unsigned y0 = cvtpk_bf16(S[base + 4], S[base + 5]); \
            pl32swap(x0, y0);                                   \
            unsigned x1 = cvtpk_bf16(S[base + 2], S[base + 3]); \
            unsigned y1 = cvtpk_bf16(S[base + 6], S[base + 7]); \
            pl32swap(x1, y1);                                   \
            pw[c][0] = x0; pw[c][1] = x1; pw[c][2] = y0; pw[c][3] = y1; \
        }
        BUILD_PA(0, s0, 0)
        BUILD_PA(1, s0, 8)
        BUILD_PA(2, s1, 0)
        BUILD_PA(3, s1, 8)
#undef BUILD_PA

        __builtin_amdgcn_s_setprio(1);
#pragma unroll
        for (int c = 0; c < 4; ++c) {
            union { unsigned u[4]; bf16x8 v; } pa;
            pa.u[0] = pw[c][0]; pa.u[1] = pw[c][1]; pa.u[2] = pw[c][2]; pa.u[3] = pw[c][3];
            const int coff = ((c * 2 + hi) ^ xr) * 8;
            bf16x8 vf0 = *(const bf16x8*)(Vb + l31 * 64 + coff);
            bf16x8 vf1 = *(const bf16x8*)(Vb + (32 + l31) * 64 + coff);
            oacc0 = __builtin_amdgcn_mfma_f32_32x32x16_bf16(pa.v, vf0, oacc0, 0, 0, 0);
            oacc1 = __builtin_amdgcn_mfma_f32_32x32x16_bf16(pa.v, vf1, oacc1, 0, 0, 0);
        }
        __builtin_amdgcn_s_setprio(0);
        __syncthreads();
    }

    // epilogue: combine half-row partials, broadcast 1/l, write O
    l_r += __shfl_xor(l_r, 32);
    if (lane < 32) Fbuf[wid][l31] = 1.0f / l_r;
    asm volatile("s_waitcnt lgkmcnt(0)" ::: "memory");
#pragma unroll
    for (int rg = 0; rg < 4; ++rg) {
#pragma unroll
        for (int rr = 0; rr < 4; ++rr) {
            int row = 8 * rg + 4 * hi + rr;
            float inv = Fbuf[wid][row];
            int r = rg * 4 + rr;
            size_t orow = (size_t)(b * S_LEN + q0 + row) * DMODEL + h * HDIM;
            aout[orow + l31] = f2bf(oacc0[r] * inv);
            aout[orow + 32 + l31] = f2bf(oacc1[r] * inv);
        }
    }
}

extern "C" void kernel_launch(void* const* d_in, const int* in_sizes, int n_in,
                              void* d_out, int out_size, void* d_ws, size_t ws_size,
                              hipStream_t stream) {
    const float* x = (const float*)d_in[0];
    const float* wq = (const float*)d_in[1];
    const float* wk = (const float*)d_in[2];
    const float* wv = (const float*)d_in[3];
    const float* wo = (const float*)d_in[4];
    const float* fc = (const float*)d_in[5];
    const float* fs = (const float*)d_in[6];
    float* out = (float*)d_out;

    unsigned short* xb = (unsigned short*)d_ws;                 // 4096x2048
    unsigned short* wqkvT = xb + (size_t)BROWS * DMODEL;        // 3072x2048
    unsigned short* woT = wqkvT + (size_t)NQKV * DMODEL;        // 2048x2048
    unsigned short* qkvb = woT + (size_t)DMODEL * DMODEL;       // 4096x3072
    unsigned short* aoutb = xb;                                 // reuse xb after GEMM1
    unsigned short* vtb = wqkvT;                                // reuse wqkvT after GEMM1

    hipError_t e1 = hipFuncSetAttribute(
        reinterpret_cast<const void*>(&gemm_wide_kernel<6, 0, 1>),
        hipFuncAttributeMaxDynamicSharedMemorySize, 131072);
    hipError_t e2 = hipFuncSetAttribute(
        reinterpret_cast<const void*>(&gemm_wide_kernel<4, 1, 0>),
        hipFuncAttributeMaxDynamicSharedMemorySize, 98304);
    const bool big = (e1 == hipSuccess && e2 == hipSuccess);

    // 1. fused prep: cast x + transpose-cast all weights (one launch)
    prep_kernel<<<18432, 256, 0, stream>>>(x, wq, wk, wv, wo, xb, wqkvT, woT);
    // 2. QKV GEMM + fused RoPE: 256 blocks, 128x384 tile
    if (big) {
        gemm_wide_kernel<6, 0, 1><<<(BROWS / 128) * (NQKV / 384), 512, 131072, stream>>>(
            xb, wqkvT, qkvb, fc, fs, BROWS, NQKV, DMODEL, NQKV / 384);
    } else {
        gemm_bt_kernel<0><<<dim3(NQKV / 128, BROWS / 128), 256, 0, stream>>>(
            xb, wqkvT, qkvb, BROWS, NQKV, DMODEL);
        rope_kernel<<<(BROWS * 1280) / 256, 256, 0, stream>>>(qkvb, fc, fs);
    }
    // 3. V transpose
    vtrans_kernel<<<dim3(S_LEN / 32, 32), 256, 0, stream>>>(qkvb, vtb);
    // 4. attention: 512 paired blocks (chunks {2z,2z+1} share K/V staging)
    attn_kernel<<<dim3(NKV, 2, 32), 512, 0, stream>>>(qkvb, vtb, aoutb);
    // 5. output GEMM: out = aoutb @ woT^T (4096x2048 f32), 128x256 tile
    if (big)
        gemm_wide_kernel<4, 1, 0><<<(BROWS / 128) * (DMODEL / 256), 512, 98304, stream>>>(
            aoutb, woT, out, nullptr, nullptr, BROWS, DMODEL, DMODEL, DMODEL / 256);
    else
        gemm_bt_kernel<1><<<dim3(DMODEL / 128, BROWS / 128), 256, 0, stream>>>(
            aoutb, woT, out, BROWS, DMODEL, DMODEL);
}